// Round 18
// baseline (319.676 us; speedup 1.0000x reference)
//
#include <hip/hip_runtime.h>
#include <stdint.h>

constexpr int kB = 8192;
constexpr int kD = 512;
constexpr int kH = 16384;
constexpr int kO = 1000;
constexpr int kNB64 = kH / 64;          // 256 candidate blocks of 64 cols
// Margin: f16-dot error (Hoeffding-effective ~0.02/score, validated by R12's
// 0.04 pass) x2 + 2x key-quantization (score low 6 bits dropped, <=0.004 each).
constexpr float kMargin = 0.055f;

typedef _Float16 half8v __attribute__((ext_vector_type(8)));
typedef _Float16 half4v __attribute__((ext_vector_type(4)));
typedef float float4v __attribute__((ext_vector_type(4)));

#define VMW(n) asm volatile("s_waitcnt vmcnt(" #n ")" ::: "memory")

// ---------------------------------------------------------------------------
// ws layout (bytes):
//   OFF_XH  : f16 x_h [8192*512]            (8 MB)
//   OFF_WH  : f16 w_h [16384*512]           (16 MB)
//   OFF_W2  : f32 w2 [16384]                (64 KB)
//   OFF_BT  : uint2 blocktop [8192][256]    (16 MB)   (k1,k2) quantized keys
//   OFF_GFT : f32 GfT [16384][1000]         (65.5 MB)
//   OFF_GRT : f32 GrT [16384][512]          (33.6 MB)
// ---------------------------------------------------------------------------
constexpr size_t OFF_XH  = 0;
constexpr size_t OFF_WH  = OFF_XH + (size_t)kB * kD * 2;
constexpr size_t OFF_W2  = OFF_WH + (size_t)kH * kD * 2;
constexpr size_t OFF_BT  = OFF_W2 + 65536;
constexpr size_t OFF_GFT = OFF_BT + (size_t)kB * kNB64 * 8;
constexpr size_t OFF_GRT = OFF_GFT + (size_t)kH * kO * 4;
constexpr size_t WS_NEED = OFF_GRT + (size_t)kH * kD * 4;

// monotone u32 key of float (smaller score -> smaller key)
__device__ inline unsigned mono32(float s) {
    unsigned u = __float_as_uint(s);
    return u ^ ((u & 0x80000000u) ? 0xFFFFFFFFu : 0x80000000u);
}
// inverse (on quantized keys: low 6 bits already masked)
__device__ inline float dq32(unsigned key) {
    unsigned u = key & 0xFFFFFFC0u;
    u ^= (u & 0x80000000u) ? 0x80000000u : 0xFFFFFFFFu;
    return __uint_as_float(u);
}
__device__ inline unsigned long long packkey(float s, int h) {
    return ((unsigned long long)mono32(s) << 32) | (unsigned)h;
}
__device__ inline unsigned long long u64min(unsigned long long a, unsigned long long b) {
    return a < b ? a : b;
}

template <typename T>
__device__ inline void gload_lds16(const T* g, T* l) {
    __builtin_amdgcn_global_load_lds(
        (const __attribute__((address_space(1))) uint32_t*)g,
        (__attribute__((address_space(3))) uint32_t*)l, 16, 0, 0);
}

// ---------------- fused prep: convert x -> f16 ; convert W -> f16 + w2 ------
__global__ __launch_bounds__(256) void prep_kernel(const float* __restrict__ x,
                                                   const float* __restrict__ W,
                                                   _Float16* __restrict__ xh,
                                                   _Float16* __restrict__ wh,
                                                   float* __restrict__ w2) {
    if (blockIdx.x < 2048) {                      // ---- x convert ----
        size_t i = (size_t)blockIdx.x * 256 + threadIdx.x;   // 8 elems per thread
        const float4* s4 = reinterpret_cast<const float4*>(x);
        float4 a = s4[i * 2], b = s4[i * 2 + 1];
        half8v h = {(_Float16)a.x, (_Float16)a.y, (_Float16)a.z, (_Float16)a.w,
                    (_Float16)b.x, (_Float16)b.y, (_Float16)b.z, (_Float16)b.w};
        *reinterpret_cast<half8v*>(xh + i * 8) = h;
    } else {                                      // ---- W convert + w2 ----
        int bx = blockIdx.x - 2048;
        int lane = threadIdx.x & 63;
        int wv   = threadIdx.x >> 6;
        int row  = bx * 4 + wv;
        const float4* Wr = reinterpret_cast<const float4*>(W + (size_t)row * kD);
        float s = 0.f;
#pragma unroll
        for (int i = 0; i < 2; ++i) {
            float4 v = Wr[lane + i * 64];
            s += v.x * v.x + v.y * v.y + v.z * v.z + v.w * v.w;
            half4v h = {(_Float16)v.x, (_Float16)v.y, (_Float16)v.z, (_Float16)v.w};
            *reinterpret_cast<half4v*>(wh + (size_t)row * kD + i * 256 + lane * 4) = h;
        }
#pragma unroll
        for (int off = 32; off; off >>= 1) s += __shfl_xor(s, off, 64);
        if (lane == 0) w2[row] = s;
    }
}

// ------- fused transposes: Gf(1000x16384)->GfT ; Gr(512x16384)->GrT ---------
__global__ __launch_bounds__(256) void transpose2_kernel(const float* __restrict__ Gf,
                                                         float* __restrict__ GfT,
                                                         const float* __restrict__ Gr,
                                                         float* __restrict__ GrT,
                                                         int useTf, int useTr) {
    const float* src; float* dst; int R, r0;
    if (blockIdx.y < 32) {
        if (!useTf) return;
        src = Gf; dst = GfT; R = kO; r0 = blockIdx.y * 32;
    } else {
        if (!useTr) return;
        src = Gr; dst = GrT; R = kD; r0 = (blockIdx.y - 32) * 32;
    }
    const int C = kH;
    __shared__ float s[32][33];
    const int tx = threadIdx.x & 31;
    const int ty = threadIdx.x >> 5;       // 0..7
    const int c0 = blockIdx.x * 32;
#pragma unroll
    for (int i = 0; i < 4; ++i) {
        int r = r0 + ty + i * 8;
        if (r < R) s[ty + i * 8][tx] = src[(size_t)r * C + c0 + tx];
    }
    __syncthreads();
#pragma unroll
    for (int i = 0; i < 4; ++i) {
        int c = c0 + ty + i * 8;
        if (r0 + tx < R) dst[(size_t)c * R + r0 + tx] = s[tx][ty + i * 8];
    }
}

// --------------------------- MFMA GEMM + per-64col top2 ---------------------
// R16 base (256x256 tile, BK=64, 128KB LDS, L2 panel swizzle, 1 barrier/tile)
// + INTRA-TILE COUNTED-lgkmcnt PIPELINE: per tile,
//   read kk0 frags(12) -> sched_barrier -> read kk1 B-frags(4) + stage 4
//   halves -> lgkmcnt(4) [kk0's 12 in-order complete; kk1-B may fly] ->
//   32 MFMA kk0 -> read kk1 A-frags(8) [scheduler may interleave with MFMA
//   drain; register deps keep it safe] -> lgkmcnt(0) -> 32 MFMA kk1 ->
//   VMW(0) -> barrier.
// Cross-wave handshake identical to R16 (verified): stages for T+1 drain at
// each wave's VMW(0) before barrier; WAR separated by barrier(T-1).
__global__ __launch_bounds__(512, 2) void gemm_argmin_mfma(
    const _Float16* __restrict__ xh, const _Float16* __restrict__ wh,
    const float* __restrict__ w2, uint2* __restrict__ blocktop)
{
    __shared__ __align__(16) _Float16 sm[65536];   // 128 KB

    const int tid  = threadIdx.x;
    const int lane = tid & 63;
    const int wv   = tid >> 6;          // 0..7
    const int wr   = wv >> 2;           // 0..1 (M)
    const int wc   = wv & 3;            // 0..3 (N)

    // L2-resident panel swizzle (R16-verified: FETCH 271MB -> 41MB)
    int bid = blockIdx.x;
    const int mb  = bid >> 6;                          // 0..31, outer
    const int hb  = (bid & 7) * 8 + ((bid >> 3) & 7);  // XCD-local 8-panel set
    const int bm0 = mb * 256, hn0 = hb * 256;

    float4v acc[8][4];
#pragma unroll
    for (int i = 0; i < 8; ++i)
#pragma unroll
        for (int j = 0; j < 4; ++j) acc[i][j] = (float4v){0.f, 0.f, 0.f, 0.f};

    // ---- stage one 16KB half-tile h (global half index 0..31) --------------
    // h = 4*T + jp ; jp: 0=A-K0, 1=B-K0, 2=A-K1, 3=B-K1 of K-tile T.
    auto STAGEH = [&](int h) {
        const int T2 = h >> 2, jp = h & 3;
        const int kk = jp >> 1, isB = jp & 1;
        const int kt = T2 * 64 + kk * 32;
        _Float16* dst0 = &sm[(((T2 & 1) << 2) | jp) * 8192 + wv * 512];
#pragma unroll
        for (int l = 0; l < 2; ++l) {
            const int idx = l * 512 + tid;        // 0..1023
            const int r = idx >> 2, c = idx & 3;  // row 0..255, chunk 0..3
            const int sc = c ^ ((r >> 1) & 3);    // pre-swizzled source chunk
            const _Float16* src =
                (isB ? wh + (size_t)(hn0 + r) * kD : xh + (size_t)(bm0 + r) * kD)
                + kt + sc * 8;
            gload_lds16(src, dst0 + l * 4096);
        }
    };

    // ---- one K-tile: pipelined kk0/kk1 halves + stage of tile hs/4 ---------
    auto TILE = [&](int buf, int hs) {
        const int fb0 = buf * 32768;              // kk0: A; B at +8192
        const int fb1 = buf * 32768 + 16384;      // kk1: A; B at +8192
        half8v bfr0[4], afr0[8], bfr1[4], afr1[8];
        // kk0 fragment reads (12) -- must be the FIRST 12 ds_reads
#pragma unroll
        for (int jn = 0; jn < 4; ++jn) {
            const int r = wc * 64 + jn * 16 + (lane & 15);
            const int cs = (lane >> 4) ^ ((r >> 1) & 3);
            bfr0[jn] = *reinterpret_cast<const half8v*>(&sm[fb0 + 8192 + r * 32 + cs * 8]);
        }
#pragma unroll
        for (int im = 0; im < 8; ++im) {
            const int r = wr * 128 + im * 16 + (lane & 15);
            const int cs = (lane >> 4) ^ ((r >> 1) & 3);
            afr0[im] = *reinterpret_cast<const half8v*>(&sm[fb0 + r * 32 + cs * 8]);
        }
        __builtin_amdgcn_sched_barrier(0);        // pin: kk0 reads strictly first
        // kk1 B fragments early (4) -- the only ds_reads allowed in flight
#pragma unroll
        for (int jn = 0; jn < 4; ++jn) {
            const int r = wc * 64 + jn * 16 + (lane & 15);
            const int cs = (lane >> 4) ^ ((r >> 1) & 3);
            bfr1[jn] = *reinterpret_cast<const half8v*>(&sm[fb1 + 8192 + r * 32 + cs * 8]);
        }
        if (hs >= 0) {                            // stage all 4 halves (vmcnt)
            STAGEH(hs); STAGEH(hs + 1); STAGEH(hs + 2); STAGEH(hs + 3);
        }
        asm volatile("s_waitcnt lgkmcnt(4)" ::: "memory");   // kk0's 12 landed
        __builtin_amdgcn_sched_barrier(0);
        __builtin_amdgcn_s_setprio(1);
#pragma unroll
        for (int im = 0; im < 8; ++im)
#pragma unroll
            for (int jn = 0; jn < 4; ++jn)
                acc[im][jn] =
                    __builtin_amdgcn_mfma_f32_16x16x32_f16(afr0[im], bfr0[jn],
                                                           acc[im][jn], 0, 0, 0);
        __builtin_amdgcn_s_setprio(0);
        // kk1 A fragments (8) -- may interleave with kk0 MFMA drain
#pragma unroll
        for (int im = 0; im < 8; ++im) {
            const int r = wr * 128 + im * 16 + (lane & 15);
            const int cs = (lane >> 4) ^ ((r >> 1) & 3);
            afr1[im] = *reinterpret_cast<const half8v*>(&sm[fb1 + r * 32 + cs * 8]);
        }
        asm volatile("s_waitcnt lgkmcnt(0)" ::: "memory");
        __builtin_amdgcn_sched_barrier(0);
        __builtin_amdgcn_s_setprio(1);
#pragma unroll
        for (int im = 0; im < 8; ++im)
#pragma unroll
            for (int jn = 0; jn < 4; ++jn)
                acc[im][jn] =
                    __builtin_amdgcn_mfma_f32_16x16x32_f16(afr1[im], bfr1[jn],
                                                           acc[im][jn], 0, 0, 0);
        __builtin_amdgcn_s_setprio(0);
    };

    // ---- prologue: stage tile 0 fully; drain; barrier ----------------------
    STAGEH(0); STAGEH(1); STAGEH(2); STAGEH(3);
    VMW(0);
    __builtin_amdgcn_s_barrier();

    // ---- 8 K-tiles, one barrier each ---------------------------------------
#pragma unroll
    for (int T = 0; T < 8; ++T) {
        TILE(T & 1, (T < 7) ? 4 * (T + 1) : -2);
        if (T < 7) {
            VMW(0);                                   // own stages for T+1 landed
            __builtin_amdgcn_s_barrier();             // all waves' stages landed
        }
    }

    // ---- epilogue: per-row top2 (quantized u32 keys) over wave's 64 cols ---
    float w2v[4];
#pragma unroll
    for (int j = 0; j < 4; ++j) w2v[j] = w2[hn0 + wc * 64 + j * 16 + (lane & 15)];

#pragma unroll
    for (int i = 0; i < 8; ++i) {
#pragma unroll
        for (int r = 0; r < 4; ++r) {
            unsigned k1 = 0xFFFFFFFFu, k2 = 0xFFFFFFFFu;
#pragma unroll
            for (int j = 0; j < 4; ++j) {
                float s = fmaf(-2.f, acc[i][j][r], w2v[j]);
                unsigned key = (mono32(s) & 0xFFFFFFC0u)
                             | (unsigned)(j * 16 + (lane & 15));   // h-in-64
                if (key < k1) { k2 = k1; k1 = key; }
                else if (key < k2) { k2 = key; }
            }
#pragma unroll
            for (int m = 1; m < 16; m <<= 1) {
                unsigned o1 = (unsigned)__shfl_xor((int)k1, m, 64);
                unsigned o2 = (unsigned)__shfl_xor((int)k2, m, 64);
                unsigned n1 = min(k1, o1);
                unsigned mx = max(k1, o1);
                k2 = min(min(k2, o2), mx);
                k1 = n1;
            }
            if ((lane & 15) == 0) {
                int rl = wr * 128 + i * 16 + (lane >> 4) * 4 + r;
                blocktop[(size_t)(bm0 + rl) * kNB64 + hb * 4 + wc] =
                    (uint2){k1, k2};
            }
        }
    }
}

// ---------------- finish: certify / exact-fp32 rescan + gather --------------
__global__ __launch_bounds__(256) void finish_kernel(
    const float* __restrict__ x, const float* __restrict__ W,
    const float* __restrict__ w2, const uint2* __restrict__ blocktop,
    const float* __restrict__ Gf, const float* __restrict__ Gr,
    const float* __restrict__ GfT, const float* __restrict__ GrT,
    int useTf, int useTr, float* __restrict__ out)
{
    const int tid = threadIdx.x;
    const int b = blockIdx.x;
    __shared__ float xs[kD];
    __shared__ unsigned long long red[256];
    __shared__ unsigned long long sv1, sv2;
    __shared__ int clist[kNB64];
    __shared__ int ccount;

    if (tid < 128)
        reinterpret_cast<float4*>(xs)[tid] =
            reinterpret_cast<const float4*>(x + (size_t)b * kD)[tid];
    if (tid == 0) ccount = 0;

    uint2 t12 = blocktop[(size_t)b * kNB64 + tid];   // 256 threads = 256 blocks

    // key40 = (quantized key32 << 8) | block-id : min = best, tie -> low block
    red[tid] = ((unsigned long long)t12.x << 8) | (unsigned)tid;
    __syncthreads();
    for (int s = 128; s > 0; s >>= 1) {
        if (tid < s) red[tid] = u64min(red[tid], red[tid + s]);
        __syncthreads();
    }
    if (tid == 0) sv1 = red[0];
    __syncthreads();
    const unsigned long long v1k = sv1;
    const int b1hb = (int)(v1k & 0xFFu);
    const unsigned v1key = (unsigned)(v1k >> 8);
    const float v1s = dq32(v1key);
    const int v1h = b1hb * 64 + (int)(v1key & 63u);

    red[tid] = ((unsigned long long)((tid == b1hb) ? t12.y : t12.x) << 8) | (unsigned)tid;
    __syncthreads();
    for (int s = 128; s > 0; s >>= 1) {
        if (tid < s) red[tid] = u64min(red[tid], red[tid + s]);
        __syncthreads();
    }
    if (tid == 0) sv2 = red[0];
    __syncthreads();
    const float v2s = dq32((unsigned)(sv2 >> 8));

    int idx;
    if (v2s - v1s > kMargin) {          // certified (block-uniform branch)
        idx = v1h;
    } else {
        // uncertain: compact candidate 64-col blocks, exact fp32 rescan,
        // one candidate block per wave, one h per lane.
        if (dq32(t12.x) <= v1s + kMargin) {
            int p = atomicAdd(&ccount, 1);
            clist[p] = tid;
        }
        __syncthreads();
        const int nc = ccount;
        const int wvf = tid >> 6, lnf = tid & 63;
        unsigned long long bestk = ~0ull;
        for (int c = wvf; c < nc; c += 4) {
            int h = clist[c] * 64 + lnf;
            const float4* wr = reinterpret_cast<const float4*>(W + (size_t)h * kD);
            float dot = 0.f;
            for (int k = 0; k < kD / 4; ++k) {
                float4 wvv = wr[k];
                dot = fmaf(xs[k * 4 + 0], wvv.x, dot);
                dot = fmaf(xs[k * 4 + 1], wvv.y, dot);
                dot = fmaf(xs[k * 4 + 2], wvv.z, dot);
                dot = fmaf(xs[k * 4 + 3], wvv.w, dot);
            }
            float s = fmaf(-2.f, dot, w2[h]);
            bestk = u64min(bestk, packkey(s, h));
        }
        red[tid] = bestk;
        __syncthreads();
        for (int s = 128; s > 0; s >>= 1) {
            if (tid < s) red[tid] = u64min(red[tid], red[tid + s]);
            __syncthreads();
        }
        idx = (int)(unsigned)(red[0] & 0xFFFFFFFFu);
    }

    float* out0 = out;                            // (B, O)
    float* out1 = out + (size_t)kB * kO;          // (B, D)
    float* outw = out + (size_t)kB * (kO + kD);   // (B,)
    if (useTf) {                                  // coalesced row gather
        const float4* gfr = reinterpret_cast<const float4*>(GfT + (size_t)idx * kO);
        float4* o0 = reinterpret_cast<float4*>(out0 + (size_t)b * kO);
        for (int o = tid; o < kO / 4; o += 256) o0[o] = gfr[o];
    } else {
        for (int o = tid; o < kO; o += 256)
            out0[(size_t)b * kO + o] = Gf[(size_t)o * kH + idx];
    }
    if (useTr) {
        const float4* grr = reinterpret_cast<const float4*>(GrT + (size_t)idx * kD);
        float4* o1 = reinterpret_cast<float4*>(out1 + (size_t)b * kD);
        if (tid < kD / 4) o1[tid] = grr[tid];
    } else {
        for (int d = tid; d < kD; d += 256)
            out1[(size_t)b * kD + d] = Gr[(size_t)d * kH + idx];
    }
    if (tid == 0) outw[b] = (float)idx;
}

extern "C" void kernel_launch(void* const* d_in, const int* in_sizes, int n_in,
                              void* d_out, int out_size, void* d_ws, size_t ws_size,
                              hipStream_t stream) {
    const float* x  = (const float*)d_in[0];
    const float* W  = (const float*)d_in[1];
    const float* Gf = (const float*)d_in[2];
    const float* Gr = (const float*)d_in[3];
    float* out = (float*)d_out;

    char* ws = (char*)d_ws;
    _Float16* xh = (_Float16*)(ws + OFF_XH);
    _Float16* wh = (_Float16*)(ws + OFF_WH);
    float* w2 = (float*)(ws + OFF_W2);
    uint2* blocktop = (uint2*)(ws + OFF_BT);
    float* GfT = (float*)(ws + OFF_GFT);
    float* GrT = (float*)(ws + OFF_GRT);
    const int useTf = (ws_size >= OFF_GRT) ? 1 : 0;
    const int useTr = (ws_size >= WS_NEED) ? 1 : 0;

    hipLaunchKernelGGL(prep_kernel, dim3(2048 + 4096), dim3(256), 0, stream,
                       x, W, xh, wh, w2);
    if (useTf || useTr)
        hipLaunchKernelGGL(transpose2_kernel, dim3(kH / 32, 48), dim3(256), 0, stream,
                           Gf, GfT, Gr, GrT, useTf, useTr);
    hipLaunchKernelGGL(gemm_argmin_mfma, dim3(2048), dim3(512), 0, stream,
                       xh, wh, w2, blocktop);
    hipLaunchKernelGGL(finish_kernel, dim3(kB), dim3(256), 0, stream,
                       x, W, w2, blocktop, Gf, Gr, GfT, GrT, useTf, useTr, out);
}

// Round 19
// 314.574 us; speedup vs baseline: 1.0162x; 1.0162x over previous
//
#include <hip/hip_runtime.h>
#include <stdint.h>

constexpr int kB = 8192;
constexpr int kD = 512;
constexpr int kH = 16384;
constexpr int kO = 1000;
constexpr int kNB64 = kH / 64;          // 256 candidate blocks of 64 cols
// Margin: f16-dot error (Hoeffding-effective ~0.02/score, validated by R12's
// 0.04 pass) x2 + 2x key-quantization (score low 6 bits dropped, <=0.004 each).
constexpr float kMargin = 0.055f;

typedef _Float16 half8v __attribute__((ext_vector_type(8)));
typedef _Float16 half4v __attribute__((ext_vector_type(4)));
typedef float float4v __attribute__((ext_vector_type(4)));

#define VMW(n) asm volatile("s_waitcnt vmcnt(" #n ")" ::: "memory")

// ---------------------------------------------------------------------------
// ws layout (bytes):
//   OFF_XH  : f16 x_h [8192*512]            (8 MB)
//   OFF_WH  : f16 w_h [16384*512]           (16 MB)
//   OFF_W2  : f32 w2 [16384]                (64 KB)
//   OFF_BT  : uint2 blocktop [8192][256]    (16 MB)   (k1,k2) quantized keys
//   OFF_GFT : f32 GfT [16384][1000]         (65.5 MB)
//   OFF_GRT : f32 GrT [16384][512]          (33.6 MB)
// ---------------------------------------------------------------------------
constexpr size_t OFF_XH  = 0;
constexpr size_t OFF_WH  = OFF_XH + (size_t)kB * kD * 2;
constexpr size_t OFF_W2  = OFF_WH + (size_t)kH * kD * 2;
constexpr size_t OFF_BT  = OFF_W2 + 65536;
constexpr size_t OFF_GFT = OFF_BT + (size_t)kB * kNB64 * 8;
constexpr size_t OFF_GRT = OFF_GFT + (size_t)kH * kO * 4;
constexpr size_t WS_NEED = OFF_GRT + (size_t)kH * kD * 4;

// monotone u32 key of float (smaller score -> smaller key)
__device__ inline unsigned mono32(float s) {
    unsigned u = __float_as_uint(s);
    return u ^ ((u & 0x80000000u) ? 0xFFFFFFFFu : 0x80000000u);
}
// inverse (on quantized keys: low 6 bits already masked)
__device__ inline float dq32(unsigned key) {
    unsigned u = key & 0xFFFFFFC0u;
    u ^= (u & 0x80000000u) ? 0x80000000u : 0xFFFFFFFFu;
    return __uint_as_float(u);
}
__device__ inline unsigned long long packkey(float s, int h) {
    return ((unsigned long long)mono32(s) << 32) | (unsigned)h;
}
__device__ inline unsigned long long u64min(unsigned long long a, unsigned long long b) {
    return a < b ? a : b;
}

template <typename T>
__device__ inline void gload_lds16(const T* g, T* l) {
    __builtin_amdgcn_global_load_lds(
        (const __attribute__((address_space(1))) uint32_t*)g,
        (__attribute__((address_space(3))) uint32_t*)l, 16, 0, 0);
}

// ------ fused prep: x->f16 | W->f16+w2 | transpose Gf | transpose Gr --------
// blocks [0,2048)            : x convert
// blocks [2048,6144)         : W convert + w2 (round-1 summation order)
// blocks [6144, 6144+24576)  : 32x32 transposes (t%512 = col tile,
//                              t/512 < 32 -> Gf row-tile, else Gr row-tile)
// All parts read only inputs and write disjoint ws regions.
__global__ __launch_bounds__(256) void prep_all_kernel(
    const float* __restrict__ x, const float* __restrict__ W,
    const float* __restrict__ Gf, const float* __restrict__ Gr,
    _Float16* __restrict__ xh, _Float16* __restrict__ wh,
    float* __restrict__ w2, float* __restrict__ GfT, float* __restrict__ GrT,
    int useTf, int useTr)
{
    if (blockIdx.x < 2048) {                      // ---- x convert ----
        size_t i = (size_t)blockIdx.x * 256 + threadIdx.x;   // 8 elems per thread
        const float4* s4 = reinterpret_cast<const float4*>(x);
        float4 a = s4[i * 2], b = s4[i * 2 + 1];
        half8v h = {(_Float16)a.x, (_Float16)a.y, (_Float16)a.z, (_Float16)a.w,
                    (_Float16)b.x, (_Float16)b.y, (_Float16)b.z, (_Float16)b.w};
        *reinterpret_cast<half8v*>(xh + i * 8) = h;
    } else if (blockIdx.x < 6144) {               // ---- W convert + w2 ----
        int bx = blockIdx.x - 2048;
        int lane = threadIdx.x & 63;
        int wv   = threadIdx.x >> 6;
        int row  = bx * 4 + wv;
        const float4* Wr = reinterpret_cast<const float4*>(W + (size_t)row * kD);
        float s = 0.f;
#pragma unroll
        for (int i = 0; i < 2; ++i) {
            float4 v = Wr[lane + i * 64];
            s += v.x * v.x + v.y * v.y + v.z * v.z + v.w * v.w;
            half4v h = {(_Float16)v.x, (_Float16)v.y, (_Float16)v.z, (_Float16)v.w};
            *reinterpret_cast<half4v*>(wh + (size_t)row * kD + i * 256 + lane * 4) = h;
        }
#pragma unroll
        for (int off = 32; off; off >>= 1) s += __shfl_xor(s, off, 64);
        if (lane == 0) w2[row] = s;
    } else {                                      // ---- transposes ----
        int t = blockIdx.x - 6144;
        int bx = t & 511;                          // col tile (kH/32 = 512)
        int ty = t >> 9;                           // 0..47
        const float* src; float* dst; int R, r0;
        if (ty < 32) {
            if (!useTf) return;
            src = Gf; dst = GfT; R = kO; r0 = ty * 32;
        } else {
            if (!useTr) return;
            src = Gr; dst = GrT; R = kD; r0 = (ty - 32) * 32;
        }
        const int C = kH;
        __shared__ float s[32][33];
        const int tx = threadIdx.x & 31;
        const int tyy = threadIdx.x >> 5;          // 0..7
        const int c0 = bx * 32;
#pragma unroll
        for (int i = 0; i < 4; ++i) {
            int r = r0 + tyy + i * 8;
            if (r < R) s[tyy + i * 8][tx] = src[(size_t)r * C + c0 + tx];
        }
        __syncthreads();
#pragma unroll
        for (int i = 0; i < 4; ++i) {
            int c = c0 + tyy + i * 8;
            if (r0 + tx < R) dst[(size_t)c * R + r0 + tx] = s[tx][tyy + i * 8];
        }
    }
}

// --------------------------- MFMA GEMM + per-64col top2 ---------------------
// R16 CHAMPION, VERBATIM (192us gemm, 315us total, passed + revalidated).
// 256x256 tile, BK=64, 8 waves (2Mx4N, wave-tile 128x64), 1 barrier/K-tile,
// L2-resident panel swizzle (FETCH 271MB -> 41MB verified).
__global__ __launch_bounds__(512, 2) void gemm_argmin_mfma(
    const _Float16* __restrict__ xh, const _Float16* __restrict__ wh,
    const float* __restrict__ w2, uint2* __restrict__ blocktop)
{
    __shared__ __align__(16) _Float16 sm[65536];   // 128 KB

    const int tid  = threadIdx.x;
    const int lane = tid & 63;
    const int wv   = tid >> 6;          // 0..7
    const int wr   = wv >> 2;           // 0..1 (M)
    const int wc   = wv & 3;            // 0..3 (N)

    // L2-resident panel swizzle (XCD = bid&7 round-robin heuristic)
    int bid = blockIdx.x;
    const int mb  = bid >> 6;                          // 0..31, outer
    const int hb  = (bid & 7) * 8 + ((bid >> 3) & 7);  // XCD-local 8-panel set
    const int bm0 = mb * 256, hn0 = hb * 256;

    float4v acc[8][4];
#pragma unroll
    for (int i = 0; i < 8; ++i)
#pragma unroll
        for (int j = 0; j < 4; ++j) acc[i][j] = (float4v){0.f, 0.f, 0.f, 0.f};

    // ---- stage one 16KB half-tile h (global half index 0..31) --------------
    // h = 4*T + jp ; jp: 0=A-K0, 1=B-K0, 2=A-K1, 3=B-K1 of K-tile T.
    auto STAGEH = [&](int h) {
        const int T2 = h >> 2, jp = h & 3;
        const int kk = jp >> 1, isB = jp & 1;
        const int kt = T2 * 64 + kk * 32;
        _Float16* dst0 = &sm[(((T2 & 1) << 2) | jp) * 8192 + wv * 512];
#pragma unroll
        for (int l = 0; l < 2; ++l) {
            const int idx = l * 512 + tid;        // 0..1023
            const int r = idx >> 2, c = idx & 3;  // row 0..255, chunk 0..3
            const int sc = c ^ ((r >> 1) & 3);    // pre-swizzled source chunk
            const _Float16* src =
                (isB ? wh + (size_t)(hn0 + r) * kD : xh + (size_t)(bm0 + r) * kD)
                + kt + sc * 8;
            gload_lds16(src, dst0 + l * 4096);
        }
    };

    // ---- one kk-half: frag reads + optional stage of 2 halves + 32 MFMA ----
    auto HALF = [&](int buf, int kk, int hstage) {
        const int fbase = buf * 32768 + kk * 16384;   // A region; B at +8192
        half8v bfr[4], afr[8];
#pragma unroll
        for (int jn = 0; jn < 4; ++jn) {
            const int r = wc * 64 + jn * 16 + (lane & 15);
            const int cs = (lane >> 4) ^ ((r >> 1) & 3);
            bfr[jn] = *reinterpret_cast<const half8v*>(&sm[fbase + 8192 + r * 32 + cs * 8]);
        }
#pragma unroll
        for (int im = 0; im < 8; ++im) {
            const int r = wr * 128 + im * 16 + (lane & 15);
            const int cs = (lane >> 4) ^ ((r >> 1) & 3);
            afr[im] = *reinterpret_cast<const half8v*>(&sm[fbase + r * 32 + cs * 8]);
        }
        if (hstage >= 0) {
            STAGEH(hstage);
            STAGEH(hstage + 1);
        }
        asm volatile("s_waitcnt lgkmcnt(0)" ::: "memory");
        __builtin_amdgcn_sched_barrier(0);
        __builtin_amdgcn_s_setprio(1);
#pragma unroll
        for (int im = 0; im < 8; ++im)
#pragma unroll
            for (int jn = 0; jn < 4; ++jn)
                acc[im][jn] =
                    __builtin_amdgcn_mfma_f32_16x16x32_f16(afr[im], bfr[jn],
                                                           acc[im][jn], 0, 0, 0);
        __builtin_amdgcn_s_setprio(0);
    };

    // ---- prologue: stage tile 0 fully; drain; barrier ----------------------
    STAGEH(0); STAGEH(1); STAGEH(2); STAGEH(3);
    VMW(0);
    __builtin_amdgcn_s_barrier();

    // ---- 8 K-tiles, one barrier each ---------------------------------------
#pragma unroll
    for (int T = 0; T < 8; ++T) {
        const int buf = T & 1;
        const int hs = (T < 7) ? 4 * (T + 1) : -2;   // stage tile T+1 (or none)
        HALF(buf, 0, hs);                             // halves hs, hs+1 (A/B-K0)
        HALF(buf, 1, hs >= 0 ? hs + 2 : -2);          // halves hs+2, hs+3 (A/B-K1)
        if (T < 7) {
            VMW(0);                                   // own stages for T+1 landed
            __builtin_amdgcn_s_barrier();             // all waves' stages landed
        }
    }

    // ---- epilogue: per-row top2 (quantized u32 keys) over wave's 64 cols ---
    float w2v[4];
#pragma unroll
    for (int j = 0; j < 4; ++j) w2v[j] = w2[hn0 + wc * 64 + j * 16 + (lane & 15)];

#pragma unroll
    for (int i = 0; i < 8; ++i) {
#pragma unroll
        for (int r = 0; r < 4; ++r) {
            unsigned k1 = 0xFFFFFFFFu, k2 = 0xFFFFFFFFu;
#pragma unroll
            for (int j = 0; j < 4; ++j) {
                float s = fmaf(-2.f, acc[i][j][r], w2v[j]);
                unsigned key = (mono32(s) & 0xFFFFFFC0u)
                             | (unsigned)(j * 16 + (lane & 15));   // h-in-64
                if (key < k1) { k2 = k1; k1 = key; }
                else if (key < k2) { k2 = key; }
            }
#pragma unroll
            for (int m = 1; m < 16; m <<= 1) {
                unsigned o1 = (unsigned)__shfl_xor((int)k1, m, 64);
                unsigned o2 = (unsigned)__shfl_xor((int)k2, m, 64);
                unsigned n1 = min(k1, o1);
                unsigned mx = max(k1, o1);
                k2 = min(min(k2, o2), mx);
                k1 = n1;
            }
            if ((lane & 15) == 0) {
                int rl = wr * 128 + i * 16 + (lane >> 4) * 4 + r;
                blocktop[(size_t)(bm0 + rl) * kNB64 + hb * 4 + wc] =
                    (uint2){k1, k2};
            }
        }
    }
}

// ---------------- finish: certify / exact-fp32 rescan + gather --------------
// R16 CHAMPION, VERBATIM.
__global__ __launch_bounds__(256) void finish_kernel(
    const float* __restrict__ x, const float* __restrict__ W,
    const float* __restrict__ w2, const uint2* __restrict__ blocktop,
    const float* __restrict__ Gf, const float* __restrict__ Gr,
    const float* __restrict__ GfT, const float* __restrict__ GrT,
    int useTf, int useTr, float* __restrict__ out)
{
    const int tid = threadIdx.x;
    const int b = blockIdx.x;
    __shared__ float xs[kD];
    __shared__ unsigned long long red[256];
    __shared__ unsigned long long sv1, sv2;
    __shared__ int clist[kNB64];
    __shared__ int ccount;

    if (tid < 128)
        reinterpret_cast<float4*>(xs)[tid] =
            reinterpret_cast<const float4*>(x + (size_t)b * kD)[tid];
    if (tid == 0) ccount = 0;

    uint2 t12 = blocktop[(size_t)b * kNB64 + tid];   // 256 threads = 256 blocks

    // key40 = (quantized key32 << 8) | block-id : min = best, tie -> low block
    red[tid] = ((unsigned long long)t12.x << 8) | (unsigned)tid;
    __syncthreads();
    for (int s = 128; s > 0; s >>= 1) {
        if (tid < s) red[tid] = u64min(red[tid], red[tid + s]);
        __syncthreads();
    }
    if (tid == 0) sv1 = red[0];
    __syncthreads();
    const unsigned long long v1k = sv1;
    const int b1hb = (int)(v1k & 0xFFu);
    const unsigned v1key = (unsigned)(v1k >> 8);
    const float v1s = dq32(v1key);
    const int v1h = b1hb * 64 + (int)(v1key & 63u);

    red[tid] = ((unsigned long long)((tid == b1hb) ? t12.y : t12.x) << 8) | (unsigned)tid;
    __syncthreads();
    for (int s = 128; s > 0; s >>= 1) {
        if (tid < s) red[tid] = u64min(red[tid], red[tid + s]);
        __syncthreads();
    }
    if (tid == 0) sv2 = red[0];
    __syncthreads();
    const float v2s = dq32((unsigned)(sv2 >> 8));

    int idx;
    if (v2s - v1s > kMargin) {          // certified (block-uniform branch)
        idx = v1h;
    } else {
        // uncertain: compact candidate 64-col blocks, exact fp32 rescan,
        // one candidate block per wave, one h per lane.
        if (dq32(t12.x) <= v1s + kMargin) {
            int p = atomicAdd(&ccount, 1);
            clist[p] = tid;
        }
        __syncthreads();
        const int nc = ccount;
        const int wvf = tid >> 6, lnf = tid & 63;
        unsigned long long bestk = ~0ull;
        for (int c = wvf; c < nc; c += 4) {
            int h = clist[c] * 64 + lnf;
            const float4* wr = reinterpret_cast<const float4*>(W + (size_t)h * kD);
            float dot = 0.f;
            for (int k = 0; k < kD / 4; ++k) {
                float4 wvv = wr[k];
                dot = fmaf(xs[k * 4 + 0], wvv.x, dot);
                dot = fmaf(xs[k * 4 + 1], wvv.y, dot);
                dot = fmaf(xs[k * 4 + 2], wvv.z, dot);
                dot = fmaf(xs[k * 4 + 3], wvv.w, dot);
            }
            float s = fmaf(-2.f, dot, w2[h]);
            bestk = u64min(bestk, packkey(s, h));
        }
        red[tid] = bestk;
        __syncthreads();
        for (int s = 128; s > 0; s >>= 1) {
            if (tid < s) red[tid] = u64min(red[tid], red[tid + s]);
            __syncthreads();
        }
        idx = (int)(unsigned)(red[0] & 0xFFFFFFFFu);
    }

    float* out0 = out;                            // (B, O)
    float* out1 = out + (size_t)kB * kO;          // (B, D)
    float* outw = out + (size_t)kB * (kO + kD);   // (B,)
    if (useTf) {                                  // coalesced row gather
        const float4* gfr = reinterpret_cast<const float4*>(GfT + (size_t)idx * kO);
        float4* o0 = reinterpret_cast<float4*>(out0 + (size_t)b * kO);
        for (int o = tid; o < kO / 4; o += 256) o0[o] = gfr[o];
    } else {
        for (int o = tid; o < kO; o += 256)
            out0[(size_t)b * kO + o] = Gf[(size_t)o * kH + idx];
    }
    if (useTr) {
        const float4* grr = reinterpret_cast<const float4*>(GrT + (size_t)idx * kD);
        float4* o1 = reinterpret_cast<float4*>(out1 + (size_t)b * kD);
        if (tid < kD / 4) o1[tid] = grr[tid];
    } else {
        for (int d = tid; d < kD; d += 256)
            out1[(size_t)b * kD + d] = Gr[(size_t)d * kH + idx];
    }
    if (tid == 0) outw[b] = (float)idx;
}

extern "C" void kernel_launch(void* const* d_in, const int* in_sizes, int n_in,
                              void* d_out, int out_size, void* d_ws, size_t ws_size,
                              hipStream_t stream) {
    const float* x  = (const float*)d_in[0];
    const float* W  = (const float*)d_in[1];
    const float* Gf = (const float*)d_in[2];
    const float* Gr = (const float*)d_in[3];
    float* out = (float*)d_out;

    char* ws = (char*)d_ws;
    _Float16* xh = (_Float16*)(ws + OFF_XH);
    _Float16* wh = (_Float16*)(ws + OFF_WH);
    float* w2 = (float*)(ws + OFF_W2);
    uint2* blocktop = (uint2*)(ws + OFF_BT);
    float* GfT = (float*)(ws + OFF_GFT);
    float* GrT = (float*)(ws + OFF_GRT);
    const int useTf = (ws_size >= OFF_GRT) ? 1 : 0;
    const int useTr = (ws_size >= WS_NEED) ? 1 : 0;

    hipLaunchKernelGGL(prep_all_kernel, dim3(6144 + 24576), dim3(256), 0, stream,
                       x, W, Gf, Gr, xh, wh, w2, GfT, GrT, useTf, useTr);
    hipLaunchKernelGGL(gemm_argmin_mfma, dim3(2048), dim3(512), 0, stream,
                       xh, wh, w2, blocktop);
    hipLaunchKernelGGL(finish_kernel, dim3(kB), dim3(256), 0, stream,
                       x, W, w2, blocktop, Gf, Gr, GfT, GrT, useTf, useTr, out);
}